// Round 1
// baseline (277.472 us; speedup 1.0000x reference)
//
#include <hip/hip_runtime.h>

// GCN: h1 = relu(Agg(x@W1) + b1); h2 = Agg(h1@W2) + b2; out = h2@Wc + bc
// Agg = symmetric-normalized adjacency with self-loops (PyG GCNConv).
// R11: fuse gemm2 into gather1 and head gemm into gather2.
//  - gather1_gemm2: 1024-thr block = 16 waves = 16 nodes (proven 1-node/wave
//    gather), relu'd rows -> fp16 LDS tile, 4 waves do 16x64 K=128 MFMA
//    with scalar L2-hot W2 frags, epilogue *dis[row] -> hw2 fp16.
//    Kills h1 store+load (25.6MB) and the gemm2 dispatch.
//  - gather2_head: same shape; writes fp32 h2 (output 0) AND stages fp16
//    rows for the 16x64 K=64 head MFMA -> out_y. Kills out_h2 re-read
//    (12.8MB) and the gemm3 dispatch.
// CSR build: XCD-partitioned hist/fill (R5), 1-kernel scan (R9). gemm1
// unchanged (R10 tile kernel).

#define DIN 128
#define HID 128
#define FOUT 64

using half8 = __attribute__((ext_vector_type(8))) _Float16;
using float8 = __attribute__((ext_vector_type(8))) float;
using f32x4 = __attribute__((ext_vector_type(4))) float;

// Deterministic dst->partition map (pure function; locality heuristic only).
__device__ inline int part_of(int d, float invn) {
  int p = (int)((float)d * invn);
  return p > 7 ? 7 : p;
}

// Partitioned histogram: block b = chunk (b>>3) x partition (b&7).
__global__ __launch_bounds__(256) void hist_kernel(
    const int* __restrict__ ei, int E, int* __restrict__ counts, float invn) {
  int part = blockIdx.x & 7;
  int e = (blockIdx.x >> 3) * 256 + threadIdx.x;
  if (e >= E) return;
  int d = ei[E + e];
  if (part_of(d, invn) == part) atomicAdd(&counts[d], 1);
}

// One-kernel scan: block b computes base = sum counts[0..b*256) directly
// (coalesced strided read), local-scans its 256 chunk, fused node_init.
__global__ __launch_bounds__(256) void scan_fused_kernel(
    const int* __restrict__ counts, int N, int E, int* __restrict__ offsets,
    int* __restrict__ cursor, float* __restrict__ dis) {
  int t = threadIdx.x;
  int start = blockIdx.x * 256;

  int partial = 0;
  for (int i = t; i < start; i += 256) partial += counts[i];
#pragma unroll
  for (int off = 32; off > 0; off >>= 1)
    partial += __shfl_down(partial, off, 64);
  __shared__ int red[4];
  if ((t & 63) == 0) red[t >> 6] = partial;
  __syncthreads();
  int base = red[0] + red[1] + red[2] + red[3];

  int i = start + t;
  int c = (i < N) ? counts[i] : 0;
  __shared__ int s[256];
  s[t] = c;
  __syncthreads();
  for (int off = 1; off < 256; off <<= 1) {
    int u = 0;
    if (t >= off) u = s[t - off];
    __syncthreads();
    s[t] += u;
    __syncthreads();
  }
  int excl = s[t] - c + base;
  if (i < N) {
    offsets[i] = excl;
    cursor[i] = excl;
    dis[i] = rsqrtf((float)c + 1.0f);  // deg includes self-loop
  }
  if (i == N - 1) offsets[N] = E;
}

// Partitioned fill: only XCD (blockIdx&7) writes partition's csr/cursor range.
__global__ __launch_bounds__(256) void fill_kernel(
    const int* __restrict__ ei, int E, int* __restrict__ cursor,
    int* __restrict__ csr, float invn) {
  int part = blockIdx.x & 7;
  int e = (blockIdx.x >> 3) * 256 + threadIdx.x;
  if (e >= E) return;
  int d = ei[E + e];
  if (part_of(d, invn) != part) return;
  int s = ei[e];
  int p = atomicAdd(&cursor[d], 1);
  csr[p] = s;
}

// Tile MFMA GEMM: C[M x NCOL] = A[M x K] @ W[K x NCOL](fp32), fp16 compute,
// fp32 accumulate. One 64-row tile per block. (Used for gemm1 only.)
template <int K, int NCOL, bool AH, bool H16, bool SCALE>
__global__ __launch_bounds__(256) void gemm_tile_kernel(
    const void* __restrict__ A, const float* __restrict__ W,
    const float* __restrict__ dis, const float* __restrict__ bias,
    void* __restrict__ Cout, int M) {
  constexpr int KP = K + 8;     // halfs; (K+8)*2 B is a 16B multiple
  constexpr int KS = K / 32;    // k-steps
  constexpr int G8 = K / 8;     // half8 groups per row
  constexpr int NW = NCOL / 4;  // cols per wave
  constexpr int CT = NW / 16;   // 16-col tiles per wave
  __shared__ _Float16 As[64 * KP];

  int tid = threadIdx.x;
  int r0 = blockIdx.x * 64;

  // stage A tile (64 x K) -> fp16 LDS, coalesced global reads
  for (int g = tid; g < 64 * G8; g += 256) {
    int row = g / G8, c8 = g % G8;
    half8 h = (half8)(_Float16)0;
    if (r0 + row < M) {
      if (AH) {
        h = *(const half8*)((const _Float16*)A + (size_t)(r0 + row) * K +
                            c8 * 8);
      } else {
        const float* ap = (const float*)A + (size_t)(r0 + row) * K + c8 * 8;
        float4 a0 = *(const float4*)ap;
        float4 a1 = *(const float4*)(ap + 4);
        h[0] = (_Float16)a0.x; h[1] = (_Float16)a0.y;
        h[2] = (_Float16)a0.z; h[3] = (_Float16)a0.w;
        h[4] = (_Float16)a1.x; h[5] = (_Float16)a1.y;
        h[6] = (_Float16)a1.z; h[7] = (_Float16)a1.w;
      }
    }
    *(half8*)&As[row * KP + c8 * 8] = h;
  }

  int wave = tid >> 6, lane = tid & 63;
  int m = lane & 15, quad = lane >> 4;
  int cw = wave * NW;

  // B fragments: B[k=quad*8+j][n=cw+ct*16+m] via scalar global loads of W
  // (coalesced across m within each quad; W is 64KB, L2-resident).
  half8 b[CT][KS];
#pragma unroll
  for (int ct = 0; ct < CT; ++ct) {
    int n = cw + ct * 16 + m;
#pragma unroll
    for (int s = 0; s < KS; ++s) {
#pragma unroll
      for (int j = 0; j < 8; ++j)
        b[ct][s][j] = (_Float16)W[(size_t)(s * 32 + quad * 8 + j) * NCOL + n];
    }
  }

  float bval[CT];
#pragma unroll
  for (int ct = 0; ct < CT; ++ct)
    bval[ct] = H16 ? 0.f : bias[cw + ct * 16 + m];

  __syncthreads();

  f32x4 acc[4][CT];
#pragma unroll
  for (int rt = 0; rt < 4; ++rt)
#pragma unroll
    for (int ct = 0; ct < CT; ++ct) acc[rt][ct] = (f32x4){0.f, 0.f, 0.f, 0.f};

#pragma unroll
  for (int rt = 0; rt < 4; ++rt) {
#pragma unroll
    for (int s = 0; s < KS; ++s) {
      half8 af = *(half8*)&As[(rt * 16 + m) * KP + s * 32 + quad * 8];
#pragma unroll
      for (int ct = 0; ct < CT; ++ct)
        acc[rt][ct] = __builtin_amdgcn_mfma_f32_16x16x32_f16(
            af, b[ct][s], acc[rt][ct], 0, 0, 0);
    }
  }

  // epilogue: C col = cw+ct*16+m, row = r0+rt*16+quad*4+i
#pragma unroll
  for (int rt = 0; rt < 4; ++rt) {
#pragma unroll
    for (int i = 0; i < 4; ++i) {
      int row = r0 + rt * 16 + quad * 4 + i;
      if (row >= M) continue;
      if (H16) {
        float d = SCALE ? dis[row] : 1.0f;
#pragma unroll
        for (int ct = 0; ct < CT; ++ct)
          ((_Float16*)Cout)[(size_t)row * NCOL + cw + ct * 16 + m] =
              (_Float16)(acc[rt][ct][i] * d);
      } else {
#pragma unroll
        for (int ct = 0; ct < CT; ++ct)
          ((float*)Cout)[(size_t)row * NCOL + cw + ct * 16 + m] =
              acc[rt][ct][i] + bval[ct];
      }
    }
  }
}

// Fused layer-1 gather + gemm2. Block = 16 waves = 16 nodes.
// Per wave (proven structure): gather UNSCALED fp16 hw1 rows with per-edge
// dis[s] weight, shuffle-reduce, h1 = relu(dn*acc + b1) -> fp16 LDS row.
// Then waves 0..3 compute the 16x64 K=128 tile (h1 @ W2)*dis -> hw2 fp16.
__global__ __launch_bounds__(1024) void gather1_gemm2_kernel(
    const _Float16* __restrict__ hw, const float* __restrict__ dis,
    const int* __restrict__ off, const int* __restrict__ csr,
    const float* __restrict__ b1, const float* __restrict__ W2,
    _Float16* __restrict__ hw2, int N) {
  constexpr int F = HID;        // 128
  constexpr int FC = F / 8;     // 16 lanes per row-chunk
  constexpr int EPW = 64 / FC;  // 4 edge slots
  constexpr int KP = F + 8;
  __shared__ _Float16 As[16 * KP];

  int wave = threadIdx.x >> 6;
  int lane = threadIdx.x & 63;
  int eslot = lane / FC;
  int c = lane % FC;
  int n = blockIdx.x * 16 + wave;

  if (n < N) {
    const half8* hw8 = (const half8*)hw;
    float dn = dis[n];
    float8 acc = {0.f, 0.f, 0.f, 0.f, 0.f, 0.f, 0.f, 0.f};
    if (eslot == 0)  // self loop: hw[n]*dn (outer *dn below gives dn^2)
      acc = __builtin_convertvector(hw8[(size_t)n * FC + c], float8) * dn;

    int j0 = off[n], j1 = off[n + 1];
    int j = j0 + eslot;
    for (; j + 3 * EPW < j1; j += 4 * EPW) {
      int s0 = csr[j + 0 * EPW];
      int s1 = csr[j + 1 * EPW];
      int s2 = csr[j + 2 * EPW];
      int s3 = csr[j + 3 * EPW];
      float d0 = dis[s0];
      float d1 = dis[s1];
      float d2 = dis[s2];
      float d3 = dis[s3];
      half8 v0 = hw8[(size_t)s0 * FC + c];
      half8 v1 = hw8[(size_t)s1 * FC + c];
      half8 v2 = hw8[(size_t)s2 * FC + c];
      half8 v3 = hw8[(size_t)s3 * FC + c];
      acc += __builtin_convertvector(v0, float8) * d0;
      acc += __builtin_convertvector(v1, float8) * d1;
      acc += __builtin_convertvector(v2, float8) * d2;
      acc += __builtin_convertvector(v3, float8) * d3;
    }
    for (; j < j1; j += EPW) {
      int s = csr[j];
      acc += __builtin_convertvector(hw8[(size_t)s * FC + c], float8) * dis[s];
    }

#pragma unroll
    for (int st = FC; st < 64; st <<= 1) {
#pragma unroll
      for (int i = 0; i < 8; ++i) acc[i] += __shfl_xor(acc[i], st, 64);
    }

    if (eslot == 0) {
      half8 h;
#pragma unroll
      for (int i = 0; i < 8; ++i)
        h[i] = (_Float16)fmaxf(fmaf(acc[i], dn, b1[c * 8 + i]), 0.f);
      *(half8*)&As[wave * KP + c * 8] = h;
    }
  } else {
    if (eslot == 0) *(half8*)&As[wave * KP + c * 8] = (half8)(_Float16)0;
  }

  // W2 fragments (loaded between gather tail and barrier; L2-hot 32KB).
  int m = lane & 15, quad = lane >> 4;
  half8 b[4];
  f32x4 a4 = {0.f, 0.f, 0.f, 0.f};
  if (wave < 4) {
    int nc = wave * 16 + m;
#pragma unroll
    for (int s = 0; s < 4; ++s)
#pragma unroll
      for (int j = 0; j < 8; ++j)
        b[s][j] = (_Float16)W2[(size_t)(s * 32 + quad * 8 + j) * FOUT + nc];
  }
  __syncthreads();

  if (wave < 4) {
#pragma unroll
    for (int s = 0; s < 4; ++s) {
      half8 af = *(half8*)&As[m * KP + s * 32 + quad * 8];
      a4 = __builtin_amdgcn_mfma_f32_16x16x32_f16(af, b[s], a4, 0, 0, 0);
    }
    int nc = wave * 16 + m;
#pragma unroll
    for (int i = 0; i < 4; ++i) {
      int row = blockIdx.x * 16 + quad * 4 + i;
      if (row < N)
        hw2[(size_t)row * FOUT + nc] = (_Float16)(a4[i] * dis[row]);
    }
  }
}

// Fused layer-2 gather + head gemm. Block = 16 waves = 16 nodes.
// Gather PRE-SCALED fp16 hw2 rows; h2 = dn*acc + b2 -> fp32 out_h2 (output 0)
// AND fp16 LDS row; waves 0..3 compute out_y = h2 @ Wc + bc (16x64, K=64).
__global__ __launch_bounds__(1024) void gather2_head_kernel(
    const _Float16* __restrict__ hw, const float* __restrict__ dis,
    const int* __restrict__ off, const int* __restrict__ csr,
    const float* __restrict__ b2, const float* __restrict__ Wc,
    const float* __restrict__ bc, float* __restrict__ out_h2,
    float* __restrict__ out_y, int N) {
  constexpr int F = FOUT;       // 64
  constexpr int FC = F / 8;     // 8 lanes per row-chunk
  constexpr int EPW = 64 / FC;  // 8 edge slots
  constexpr int KP = F + 8;
  __shared__ _Float16 As[16 * KP];

  int wave = threadIdx.x >> 6;
  int lane = threadIdx.x & 63;
  int eslot = lane / FC;
  int c = lane % FC;
  int n = blockIdx.x * 16 + wave;

  if (n < N) {
    const half8* hw8 = (const half8*)hw;
    float8 acc = {0.f, 0.f, 0.f, 0.f, 0.f, 0.f, 0.f, 0.f};
    if (eslot == 0)  // self loop (row pre-scaled by dis[n])
      acc = __builtin_convertvector(hw8[(size_t)n * FC + c], float8);

    int j0 = off[n], j1 = off[n + 1];
    int j = j0 + eslot;
    for (; j + 3 * EPW < j1; j += 4 * EPW) {
      int s0 = csr[j + 0 * EPW];
      int s1 = csr[j + 1 * EPW];
      int s2 = csr[j + 2 * EPW];
      int s3 = csr[j + 3 * EPW];
      half8 v0 = hw8[(size_t)s0 * FC + c];
      half8 v1 = hw8[(size_t)s1 * FC + c];
      half8 v2 = hw8[(size_t)s2 * FC + c];
      half8 v3 = hw8[(size_t)s3 * FC + c];
      acc += __builtin_convertvector(v0, float8);
      acc += __builtin_convertvector(v1, float8);
      acc += __builtin_convertvector(v2, float8);
      acc += __builtin_convertvector(v3, float8);
    }
    for (; j < j1; j += EPW)
      acc += __builtin_convertvector(hw8[(size_t)csr[j] * FC + c], float8);

#pragma unroll
    for (int st = FC; st < 64; st <<= 1) {
#pragma unroll
      for (int i = 0; i < 8; ++i) acc[i] += __shfl_xor(acc[i], st, 64);
    }

    if (eslot == 0) {
      float dn = dis[n];
      float4 bb0 = *(const float4*)&b2[c * 8 + 0];
      float4 bb1 = *(const float4*)&b2[c * 8 + 4];
      float4 r0 = make_float4(fmaf(acc[0], dn, bb0.x), fmaf(acc[1], dn, bb0.y),
                              fmaf(acc[2], dn, bb0.z), fmaf(acc[3], dn, bb0.w));
      float4 r1 = make_float4(fmaf(acc[4], dn, bb1.x), fmaf(acc[5], dn, bb1.y),
                              fmaf(acc[6], dn, bb1.z), fmaf(acc[7], dn, bb1.w));
      float* op = out_h2 + (size_t)n * F + c * 8;
      *(float4*)(op + 0) = r0;
      *(float4*)(op + 4) = r1;
      half8 h;
      h[0] = (_Float16)r0.x; h[1] = (_Float16)r0.y;
      h[2] = (_Float16)r0.z; h[3] = (_Float16)r0.w;
      h[4] = (_Float16)r1.x; h[5] = (_Float16)r1.y;
      h[6] = (_Float16)r1.z; h[7] = (_Float16)r1.w;
      *(half8*)&As[wave * KP + c * 8] = h;
    }
  } else {
    if (eslot == 0) *(half8*)&As[wave * KP + c * 8] = (half8)(_Float16)0;
  }

  // Wc fragments (16KB, L2-hot), K=64 -> 2 k-steps.
  int m = lane & 15, quad = lane >> 4;
  half8 b[2];
  float bval = 0.f;
  f32x4 a4 = {0.f, 0.f, 0.f, 0.f};
  if (wave < 4) {
    int nc = wave * 16 + m;
#pragma unroll
    for (int s = 0; s < 2; ++s)
#pragma unroll
      for (int j = 0; j < 8; ++j)
        b[s][j] = (_Float16)Wc[(size_t)(s * 32 + quad * 8 + j) * FOUT + nc];
    bval = bc[nc];
  }
  __syncthreads();

  if (wave < 4) {
#pragma unroll
    for (int s = 0; s < 2; ++s) {
      half8 af = *(half8*)&As[m * KP + s * 32 + quad * 8];
      a4 = __builtin_amdgcn_mfma_f32_16x16x32_f16(af, b[s], a4, 0, 0, 0);
    }
    int nc = wave * 16 + m;
#pragma unroll
    for (int i = 0; i < 4; ++i) {
      int row = blockIdx.x * 16 + quad * 4 + i;
      if (row < N) out_y[(size_t)row * FOUT + nc] = a4[i] + bval;
    }
  }
}

extern "C" void kernel_launch(void* const* d_in, const int* in_sizes, int n_in,
                              void* d_out, int out_size, void* d_ws,
                              size_t ws_size, hipStream_t stream) {
  const float* x = (const float*)d_in[0];
  const int* ei = (const int*)d_in[1];
  const float* W1 = (const float*)d_in[2];
  const float* b1 = (const float*)d_in[3];
  const float* W2 = (const float*)d_in[4];
  const float* b2 = (const float*)d_in[5];
  const float* Wc = (const float*)d_in[6];
  const float* bc = (const float*)d_in[7];

  int N = in_sizes[0] / DIN;
  int E = in_sizes[1] / 2;
  int nper = (N + 7) / 8;           // dst-range partition size
  float invn = 1.0f / (float)nper;  // deterministic partition map scale

  char* w = (char*)d_ws;
  size_t off = 0;
  auto alloc = [&](size_t bytes) {
    char* p = w + off;
    off += (bytes + 255) & ~(size_t)255;
    return p;
  };
  int* counts = (int*)alloc((size_t)N * 4);
  int* offsets = (int*)alloc((size_t)(N + 1) * 4);
  int* cursor = (int*)alloc((size_t)N * 4);
  int* csr = (int*)alloc((size_t)E * 4);
  float* dis = (float*)alloc((size_t)N * 4);
  _Float16* hw1 = (_Float16*)alloc((size_t)N * DIN * 2);   // fp16, UNscaled
  _Float16* hw2 = (_Float16*)alloc((size_t)N * FOUT * 2);  // fp16, pre-scaled

  float* out_h2 = (float*)d_out;             // output 0: h2 [N x 64]
  float* out_y = out_h2 + (size_t)N * FOUT;  // output 1: out [N x 64]

  hipMemsetAsync(counts, 0, (size_t)N * 4, stream);

  int egrid = (E + 255) / 256;
  int ngrid = (N + 255) / 256;
  int tgrid = (N + 63) / 64;   // gemm1: one 64-row tile per block
  int fgrid = (N + 15) / 16;   // fused gather+gemm: 16 nodes per block

  hist_kernel<<<egrid * 8, 256, 0, stream>>>(ei, E, counts, invn);
  scan_fused_kernel<<<ngrid, 256, 0, stream>>>(counts, N, E, offsets, cursor,
                                               dis);
  fill_kernel<<<egrid * 8, 256, 0, stream>>>(ei, E, cursor, csr, invn);

  // layer 1 transform: hw1 = x @ W1 (fp16, unscaled)
  gemm_tile_kernel<DIN, HID, false, true, false><<<tgrid, 256, 0, stream>>>(
      x, W1, nullptr, nullptr, hw1, N);

  // fused: h1 = relu(dn*Agg(hw1*ds) + b1); hw2 = (h1 @ W2)*dis (fp16)
  gather1_gemm2_kernel<<<fgrid, 1024, 0, stream>>>(hw1, dis, offsets, csr, b1,
                                                   W2, hw2, N);

  // fused: h2 = dn*Agg(hw2) + b2 -> out_h2 (fp32); out_y = h2 @ Wc + bc
  gather2_head_kernel<<<fgrid, 1024, 0, stream>>>(hw2, dis, offsets, csr, b2,
                                                  Wc, bc, out_h2, out_y, N);
}

// Round 2
// 269.517 us; speedup vs baseline: 1.0295x; 1.0295x over previous
//
#include <hip/hip_runtime.h>

// GCN: h1 = relu(Agg(x@W1) + b1); h2 = Agg(h1@W2) + b2; out = h2@Wc + bc
// Agg = symmetric-normalized adjacency with self-loops (PyG GCNConv).
// R12: fix the latency-bound gathers (R11 post-mortem: VGPR=32 serialized
// the row loads to ~1 in flight; dur flat at 48us even with cache-hot data).
//  - gemm1 now pre-scales rows by dis[row] (SCALE=true) -> gather1 loses the
//    per-edge dependent dis[s] load chain entirely (same scheme layer 2
//    already used).
//  - Both gathers: two independent f32x8 accumulators (no serial add chain),
//    loads grouped before uses, and the serial remainder loop replaced by a
//    single masked 4-deep batch (mask-by-multiply, branchless). Max ~16-32
//    rows in flight per wave instead of ~1.
//  - __launch_bounds__(1024, 4): VGPR cap 128 (~60 needed) so the allocator
//    can keep the batch live.
// CSR build: XCD-partitioned hist/fill (R5), 1-kernel scan (R9). gemm1
// tile kernel unchanged otherwise.

#define DIN 128
#define HID 128
#define FOUT 64

using half8 = __attribute__((ext_vector_type(8))) _Float16;
using float8 = __attribute__((ext_vector_type(8))) float;
using f32x4 = __attribute__((ext_vector_type(4))) float;

__device__ inline float8 cvt8(half8 v) {
  return __builtin_convertvector(v, float8);
}

// Deterministic dst->partition map (pure function; locality heuristic only).
__device__ inline int part_of(int d, float invn) {
  int p = (int)((float)d * invn);
  return p > 7 ? 7 : p;
}

// Partitioned histogram: block b = chunk (b>>3) x partition (b&7).
__global__ __launch_bounds__(256) void hist_kernel(
    const int* __restrict__ ei, int E, int* __restrict__ counts, float invn) {
  int part = blockIdx.x & 7;
  int e = (blockIdx.x >> 3) * 256 + threadIdx.x;
  if (e >= E) return;
  int d = ei[E + e];
  if (part_of(d, invn) == part) atomicAdd(&counts[d], 1);
}

// One-kernel scan: block b computes base = sum counts[0..b*256) directly
// (coalesced strided read), local-scans its 256 chunk, fused node_init.
__global__ __launch_bounds__(256) void scan_fused_kernel(
    const int* __restrict__ counts, int N, int E, int* __restrict__ offsets,
    int* __restrict__ cursor, float* __restrict__ dis) {
  int t = threadIdx.x;
  int start = blockIdx.x * 256;

  int partial = 0;
  for (int i = t; i < start; i += 256) partial += counts[i];
#pragma unroll
  for (int off = 32; off > 0; off >>= 1)
    partial += __shfl_down(partial, off, 64);
  __shared__ int red[4];
  if ((t & 63) == 0) red[t >> 6] = partial;
  __syncthreads();
  int base = red[0] + red[1] + red[2] + red[3];

  int i = start + t;
  int c = (i < N) ? counts[i] : 0;
  __shared__ int s[256];
  s[t] = c;
  __syncthreads();
  for (int off = 1; off < 256; off <<= 1) {
    int u = 0;
    if (t >= off) u = s[t - off];
    __syncthreads();
    s[t] += u;
    __syncthreads();
  }
  int excl = s[t] - c + base;
  if (i < N) {
    offsets[i] = excl;
    cursor[i] = excl;
    dis[i] = rsqrtf((float)c + 1.0f);  // deg includes self-loop
  }
  if (i == N - 1) offsets[N] = E;
}

// Partitioned fill: only XCD (blockIdx&7) writes partition's csr/cursor range.
__global__ __launch_bounds__(256) void fill_kernel(
    const int* __restrict__ ei, int E, int* __restrict__ cursor,
    int* __restrict__ csr, float invn) {
  int part = blockIdx.x & 7;
  int e = (blockIdx.x >> 3) * 256 + threadIdx.x;
  if (e >= E) return;
  int d = ei[E + e];
  if (part_of(d, invn) != part) return;
  int s = ei[e];
  int p = atomicAdd(&cursor[d], 1);
  csr[p] = s;
}

// Tile MFMA GEMM: C[M x NCOL] = A[M x K] @ W[K x NCOL](fp32), fp16 compute,
// fp32 accumulate. One 64-row tile per block. (Used for gemm1 only.)
template <int K, int NCOL, bool AH, bool H16, bool SCALE>
__global__ __launch_bounds__(256) void gemm_tile_kernel(
    const void* __restrict__ A, const float* __restrict__ W,
    const float* __restrict__ dis, const float* __restrict__ bias,
    void* __restrict__ Cout, int M) {
  constexpr int KP = K + 8;     // halfs; (K+8)*2 B is a 16B multiple
  constexpr int KS = K / 32;    // k-steps
  constexpr int G8 = K / 8;     // half8 groups per row
  constexpr int NW = NCOL / 4;  // cols per wave
  constexpr int CT = NW / 16;   // 16-col tiles per wave
  __shared__ _Float16 As[64 * KP];

  int tid = threadIdx.x;
  int r0 = blockIdx.x * 64;

  // stage A tile (64 x K) -> fp16 LDS, coalesced global reads
  for (int g = tid; g < 64 * G8; g += 256) {
    int row = g / G8, c8 = g % G8;
    half8 h = (half8)(_Float16)0;
    if (r0 + row < M) {
      if (AH) {
        h = *(const half8*)((const _Float16*)A + (size_t)(r0 + row) * K +
                            c8 * 8);
      } else {
        const float* ap = (const float*)A + (size_t)(r0 + row) * K + c8 * 8;
        float4 a0 = *(const float4*)ap;
        float4 a1 = *(const float4*)(ap + 4);
        h[0] = (_Float16)a0.x; h[1] = (_Float16)a0.y;
        h[2] = (_Float16)a0.z; h[3] = (_Float16)a0.w;
        h[4] = (_Float16)a1.x; h[5] = (_Float16)a1.y;
        h[6] = (_Float16)a1.z; h[7] = (_Float16)a1.w;
      }
    }
    *(half8*)&As[row * KP + c8 * 8] = h;
  }

  int wave = tid >> 6, lane = tid & 63;
  int m = lane & 15, quad = lane >> 4;
  int cw = wave * NW;

  // B fragments: B[k=quad*8+j][n=cw+ct*16+m] via scalar global loads of W
  // (coalesced across m within each quad; W is 64KB, L2-resident).
  half8 b[CT][KS];
#pragma unroll
  for (int ct = 0; ct < CT; ++ct) {
    int n = cw + ct * 16 + m;
#pragma unroll
    for (int s = 0; s < KS; ++s) {
#pragma unroll
      for (int j = 0; j < 8; ++j)
        b[ct][s][j] = (_Float16)W[(size_t)(s * 32 + quad * 8 + j) * NCOL + n];
    }
  }

  float bval[CT];
#pragma unroll
  for (int ct = 0; ct < CT; ++ct)
    bval[ct] = H16 ? 0.f : bias[cw + ct * 16 + m];

  __syncthreads();

  f32x4 acc[4][CT];
#pragma unroll
  for (int rt = 0; rt < 4; ++rt)
#pragma unroll
    for (int ct = 0; ct < CT; ++ct) acc[rt][ct] = (f32x4){0.f, 0.f, 0.f, 0.f};

#pragma unroll
  for (int rt = 0; rt < 4; ++rt) {
#pragma unroll
    for (int s = 0; s < KS; ++s) {
      half8 af = *(half8*)&As[(rt * 16 + m) * KP + s * 32 + quad * 8];
#pragma unroll
      for (int ct = 0; ct < CT; ++ct)
        acc[rt][ct] = __builtin_amdgcn_mfma_f32_16x16x32_f16(
            af, b[ct][s], acc[rt][ct], 0, 0, 0);
    }
  }

  // epilogue: C col = cw+ct*16+m, row = r0+rt*16+quad*4+i
#pragma unroll
  for (int rt = 0; rt < 4; ++rt) {
#pragma unroll
    for (int i = 0; i < 4; ++i) {
      int row = r0 + rt * 16 + quad * 4 + i;
      if (row >= M) continue;
      if (H16) {
        float d = SCALE ? dis[row] : 1.0f;
#pragma unroll
        for (int ct = 0; ct < CT; ++ct)
          ((_Float16*)Cout)[(size_t)row * NCOL + cw + ct * 16 + m] =
              (_Float16)(acc[rt][ct][i] * d);
      } else {
#pragma unroll
        for (int ct = 0; ct < CT; ++ct)
          ((float*)Cout)[(size_t)row * NCOL + cw + ct * 16 + m] =
              acc[rt][ct][i] + bval[ct];
      }
    }
  }
}

// Fused layer-1 gather + gemm2. Block = 16 waves = 16 nodes.
// hw rows are PRE-SCALED by dis[row] (gemm1 epilogue), so the gather is a
// pure row-sum: h1 = relu(dn*(sum hws[s] + hws[n]) + b1) -> fp16 LDS row.
// Then waves 0..3 compute the 16x64 K=128 tile (h1 @ W2)*dis -> hw2 fp16.
__global__ __launch_bounds__(1024, 4) void gather1_gemm2_kernel(
    const _Float16* __restrict__ hw, const float* __restrict__ dis,
    const int* __restrict__ off, const int* __restrict__ csr,
    const float* __restrict__ b1, const float* __restrict__ W2,
    _Float16* __restrict__ hw2, int N) {
  constexpr int F = HID;        // 128
  constexpr int FC = F / 8;     // 16 lanes per row-chunk
  constexpr int EPW = 64 / FC;  // 4 edge slots
  constexpr int KP = F + 8;
  __shared__ _Float16 As[16 * KP];

  int wave = threadIdx.x >> 6;
  int lane = threadIdx.x & 63;
  int eslot = lane / FC;
  int c = lane % FC;
  int n = blockIdx.x * 16 + wave;

  if (n < N) {
    const half8* hw8 = (const half8*)hw;
    float8 acc0 = {0.f, 0.f, 0.f, 0.f, 0.f, 0.f, 0.f, 0.f};
    float8 acc1 = {0.f, 0.f, 0.f, 0.f, 0.f, 0.f, 0.f, 0.f};
    if (eslot == 0)  // self loop: hws[n] (outer *dn gives dn^2*hw[n])
      acc0 = cvt8(hw8[(size_t)n * FC + c]);

    int j0 = off[n], j1 = off[n + 1];
    int j = j0 + eslot;
    // main: 4 rows in flight per lane-group (16/wave), independent accs
    for (; j + 3 * EPW < j1; j += 4 * EPW) {
      int s0 = csr[j + 0 * EPW];
      int s1 = csr[j + 1 * EPW];
      int s2 = csr[j + 2 * EPW];
      int s3 = csr[j + 3 * EPW];
      half8 v0 = hw8[(size_t)s0 * FC + c];
      half8 v1 = hw8[(size_t)s1 * FC + c];
      half8 v2 = hw8[(size_t)s2 * FC + c];
      half8 v3 = hw8[(size_t)s3 * FC + c];
      acc0 += cvt8(v0);
      acc1 += cvt8(v1);
      acc0 += cvt8(v2);
      acc1 += cvt8(v3);
    }
    // masked tail batch: all residual rows in flight at once (no serial
    // csr->row round-trips). mask-by-multiply, branchless.
    if (j < j1) {
      int i1 = j + 1 * EPW, i2 = j + 2 * EPW, i3 = j + 3 * EPW;
      int s0 = csr[j];
      int s1 = csr[i1 < j1 ? i1 : j];
      int s2 = csr[i2 < j1 ? i2 : j];
      int s3 = csr[i3 < j1 ? i3 : j];
      float m1 = i1 < j1 ? 1.f : 0.f;
      float m2 = i2 < j1 ? 1.f : 0.f;
      float m3 = i3 < j1 ? 1.f : 0.f;
      half8 v0 = hw8[(size_t)s0 * FC + c];
      half8 v1 = hw8[(size_t)s1 * FC + c];
      half8 v2 = hw8[(size_t)s2 * FC + c];
      half8 v3 = hw8[(size_t)s3 * FC + c];
      acc0 += cvt8(v0);
      acc1 += cvt8(v1) * m1;
      acc0 += cvt8(v2) * m2;
      acc1 += cvt8(v3) * m3;
    }
    acc0 += acc1;

#pragma unroll
    for (int st = FC; st < 64; st <<= 1) {
#pragma unroll
      for (int i = 0; i < 8; ++i) acc0[i] += __shfl_xor(acc0[i], st, 64);
    }

    if (eslot == 0) {
      float dn = dis[n];
      half8 h;
#pragma unroll
      for (int i = 0; i < 8; ++i)
        h[i] = (_Float16)fmaxf(fmaf(acc0[i], dn, b1[c * 8 + i]), 0.f);
      *(half8*)&As[wave * KP + c * 8] = h;
    }
  } else {
    if (eslot == 0) *(half8*)&As[wave * KP + c * 8] = (half8)(_Float16)0;
  }

  // W2 fragments (loaded between gather tail and barrier; L2-hot 32KB).
  int m = lane & 15, quad = lane >> 4;
  half8 b[4];
  f32x4 a4 = {0.f, 0.f, 0.f, 0.f};
  if (wave < 4) {
    int nc = wave * 16 + m;
#pragma unroll
    for (int s = 0; s < 4; ++s)
#pragma unroll
      for (int j = 0; j < 8; ++j)
        b[s][j] = (_Float16)W2[(size_t)(s * 32 + quad * 8 + j) * FOUT + nc];
  }
  __syncthreads();

  if (wave < 4) {
#pragma unroll
    for (int s = 0; s < 4; ++s) {
      half8 af = *(half8*)&As[m * KP + s * 32 + quad * 8];
      a4 = __builtin_amdgcn_mfma_f32_16x16x32_f16(af, b[s], a4, 0, 0, 0);
    }
    int nc = wave * 16 + m;
#pragma unroll
    for (int i = 0; i < 4; ++i) {
      int row = blockIdx.x * 16 + quad * 4 + i;
      if (row < N)
        hw2[(size_t)row * FOUT + nc] = (_Float16)(a4[i] * dis[row]);
    }
  }
}

// Fused layer-2 gather + head gemm. Block = 16 waves = 16 nodes.
// Gather PRE-SCALED fp16 hw2 rows; h2 = dn*acc + b2 -> fp32 out_h2 (output 0)
// AND fp16 LDS row; waves 0..3 compute out_y = h2 @ Wc + bc (16x64, K=64).
__global__ __launch_bounds__(1024, 4) void gather2_head_kernel(
    const _Float16* __restrict__ hw, const float* __restrict__ dis,
    const int* __restrict__ off, const int* __restrict__ csr,
    const float* __restrict__ b2, const float* __restrict__ Wc,
    const float* __restrict__ bc, float* __restrict__ out_h2,
    float* __restrict__ out_y, int N) {
  constexpr int F = FOUT;       // 64
  constexpr int FC = F / 8;     // 8 lanes per row-chunk
  constexpr int EPW = 64 / FC;  // 8 edge slots
  constexpr int KP = F + 8;
  __shared__ _Float16 As[16 * KP];

  int wave = threadIdx.x >> 6;
  int lane = threadIdx.x & 63;
  int eslot = lane / FC;
  int c = lane % FC;
  int n = blockIdx.x * 16 + wave;

  if (n < N) {
    const half8* hw8 = (const half8*)hw;
    float8 acc0 = {0.f, 0.f, 0.f, 0.f, 0.f, 0.f, 0.f, 0.f};
    float8 acc1 = {0.f, 0.f, 0.f, 0.f, 0.f, 0.f, 0.f, 0.f};
    if (eslot == 0)  // self loop (row pre-scaled by dis[n])
      acc0 = cvt8(hw8[(size_t)n * FC + c]);

    int j0 = off[n], j1 = off[n + 1];
    int j = j0 + eslot;
    for (; j + 3 * EPW < j1; j += 4 * EPW) {
      int s0 = csr[j + 0 * EPW];
      int s1 = csr[j + 1 * EPW];
      int s2 = csr[j + 2 * EPW];
      int s3 = csr[j + 3 * EPW];
      half8 v0 = hw8[(size_t)s0 * FC + c];
      half8 v1 = hw8[(size_t)s1 * FC + c];
      half8 v2 = hw8[(size_t)s2 * FC + c];
      half8 v3 = hw8[(size_t)s3 * FC + c];
      acc0 += cvt8(v0);
      acc1 += cvt8(v1);
      acc0 += cvt8(v2);
      acc1 += cvt8(v3);
    }
    if (j < j1) {
      int i1 = j + 1 * EPW, i2 = j + 2 * EPW, i3 = j + 3 * EPW;
      int s0 = csr[j];
      int s1 = csr[i1 < j1 ? i1 : j];
      int s2 = csr[i2 < j1 ? i2 : j];
      int s3 = csr[i3 < j1 ? i3 : j];
      float m1 = i1 < j1 ? 1.f : 0.f;
      float m2 = i2 < j1 ? 1.f : 0.f;
      float m3 = i3 < j1 ? 1.f : 0.f;
      half8 v0 = hw8[(size_t)s0 * FC + c];
      half8 v1 = hw8[(size_t)s1 * FC + c];
      half8 v2 = hw8[(size_t)s2 * FC + c];
      half8 v3 = hw8[(size_t)s3 * FC + c];
      acc0 += cvt8(v0);
      acc1 += cvt8(v1) * m1;
      acc0 += cvt8(v2) * m2;
      acc1 += cvt8(v3) * m3;
    }
    acc0 += acc1;

#pragma unroll
    for (int st = FC; st < 64; st <<= 1) {
#pragma unroll
      for (int i = 0; i < 8; ++i) acc0[i] += __shfl_xor(acc0[i], st, 64);
    }

    if (eslot == 0) {
      float dn = dis[n];
      float4 bb0 = *(const float4*)&b2[c * 8 + 0];
      float4 bb1 = *(const float4*)&b2[c * 8 + 4];
      float4 r0 =
          make_float4(fmaf(acc0[0], dn, bb0.x), fmaf(acc0[1], dn, bb0.y),
                      fmaf(acc0[2], dn, bb0.z), fmaf(acc0[3], dn, bb0.w));
      float4 r1 =
          make_float4(fmaf(acc0[4], dn, bb1.x), fmaf(acc0[5], dn, bb1.y),
                      fmaf(acc0[6], dn, bb1.z), fmaf(acc0[7], dn, bb1.w));
      float* op = out_h2 + (size_t)n * F + c * 8;
      *(float4*)(op + 0) = r0;
      *(float4*)(op + 4) = r1;
      half8 h;
      h[0] = (_Float16)r0.x; h[1] = (_Float16)r0.y;
      h[2] = (_Float16)r0.z; h[3] = (_Float16)r0.w;
      h[4] = (_Float16)r1.x; h[5] = (_Float16)r1.y;
      h[6] = (_Float16)r1.z; h[7] = (_Float16)r1.w;
      *(half8*)&As[wave * KP + c * 8] = h;
    }
  } else {
    if (eslot == 0) *(half8*)&As[wave * KP + c * 8] = (half8)(_Float16)0;
  }

  // Wc fragments (16KB, L2-hot), K=64 -> 2 k-steps.
  int m = lane & 15, quad = lane >> 4;
  half8 b[2];
  float bval = 0.f;
  f32x4 a4 = {0.f, 0.f, 0.f, 0.f};
  if (wave < 4) {
    int nc = wave * 16 + m;
#pragma unroll
    for (int s = 0; s < 2; ++s)
#pragma unroll
      for (int j = 0; j < 8; ++j)
        b[s][j] = (_Float16)Wc[(size_t)(s * 32 + quad * 8 + j) * FOUT + nc];
    bval = bc[nc];
  }
  __syncthreads();

  if (wave < 4) {
#pragma unroll
    for (int s = 0; s < 2; ++s) {
      half8 af = *(half8*)&As[m * KP + s * 32 + quad * 8];
      a4 = __builtin_amdgcn_mfma_f32_16x16x32_f16(af, b[s], a4, 0, 0, 0);
    }
    int nc = wave * 16 + m;
#pragma unroll
    for (int i = 0; i < 4; ++i) {
      int row = blockIdx.x * 16 + quad * 4 + i;
      if (row < N) out_y[(size_t)row * FOUT + nc] = a4[i] + bval;
    }
  }
}

extern "C" void kernel_launch(void* const* d_in, const int* in_sizes, int n_in,
                              void* d_out, int out_size, void* d_ws,
                              size_t ws_size, hipStream_t stream) {
  const float* x = (const float*)d_in[0];
  const int* ei = (const int*)d_in[1];
  const float* W1 = (const float*)d_in[2];
  const float* b1 = (const float*)d_in[3];
  const float* W2 = (const float*)d_in[4];
  const float* b2 = (const float*)d_in[5];
  const float* Wc = (const float*)d_in[6];
  const float* bc = (const float*)d_in[7];

  int N = in_sizes[0] / DIN;
  int E = in_sizes[1] / 2;
  int nper = (N + 7) / 8;           // dst-range partition size
  float invn = 1.0f / (float)nper;  // deterministic partition map scale

  char* w = (char*)d_ws;
  size_t off = 0;
  auto alloc = [&](size_t bytes) {
    char* p = w + off;
    off += (bytes + 255) & ~(size_t)255;
    return p;
  };
  int* counts = (int*)alloc((size_t)N * 4);
  int* offsets = (int*)alloc((size_t)(N + 1) * 4);
  int* cursor = (int*)alloc((size_t)N * 4);
  int* csr = (int*)alloc((size_t)E * 4);
  float* dis = (float*)alloc((size_t)N * 4);
  _Float16* hw1 = (_Float16*)alloc((size_t)N * DIN * 2);   // fp16, PRE-scaled
  _Float16* hw2 = (_Float16*)alloc((size_t)N * FOUT * 2);  // fp16, PRE-scaled

  float* out_h2 = (float*)d_out;             // output 0: h2 [N x 64]
  float* out_y = out_h2 + (size_t)N * FOUT;  // output 1: out [N x 64]

  hipMemsetAsync(counts, 0, (size_t)N * 4, stream);

  int egrid = (E + 255) / 256;
  int ngrid = (N + 255) / 256;
  int tgrid = (N + 63) / 64;  // gemm1: one 64-row tile per block
  int fgrid = (N + 15) / 16;  // fused gather+gemm: 16 nodes per block

  hist_kernel<<<egrid * 8, 256, 0, stream>>>(ei, E, counts, invn);
  scan_fused_kernel<<<ngrid, 256, 0, stream>>>(counts, N, E, offsets, cursor,
                                               dis);
  fill_kernel<<<egrid * 8, 256, 0, stream>>>(ei, E, cursor, csr, invn);

  // layer 1 transform: hw1 = (x @ W1)*dis (fp16, pre-scaled)
  gemm_tile_kernel<DIN, HID, false, true, true><<<tgrid, 256, 0, stream>>>(
      x, W1, dis, nullptr, hw1, N);

  // fused: h1 = relu(dn*Agg(hws1) + b1); hw2 = (h1 @ W2)*dis (fp16)
  gather1_gemm2_kernel<<<fgrid, 1024, 0, stream>>>(hw1, dis, offsets, csr, b1,
                                                   W2, hw2, N);

  // fused: h2 = dn*Agg(hws2) + b2 -> out_h2 (fp32); out_y = h2 @ Wc + bc
  gather2_head_kernel<<<fgrid, 1024, 0, stream>>>(hw2, dis, offsets, csr, b2,
                                                  Wc, bc, out_h2, out_y, N);
}